// Round 5
// baseline (1565.174 us; speedup 1.0000x reference)
//
#include <hip/hip_runtime.h>
#include <hip/hip_bf16.h>

#define LN_EPS 1e-5f
#define HB 64          // histogram blocks
#define HSEG 12800     // histogram LDS segment (51.2 KB)
#define NBLK 128       // binning blocks
#define BROWS 64       // rows per dst bucket

typedef __attribute__((ext_vector_type(8))) short short8;
typedef __attribute__((ext_vector_type(4))) float f32x4;

// ---- bf16 helpers (bit-level, RNE) ----
__device__ __forceinline__ unsigned short f2bf(float f) {
    unsigned int u = __float_as_uint(f);
    u += 0x7fffu + ((u >> 16) & 1u);
    return (unsigned short)(u >> 16);
}
__device__ __forceinline__ unsigned int pack2bf(float a, float b) {
    return (unsigned int)f2bf(a) | ((unsigned int)f2bf(b) << 16);
}
__device__ __forceinline__ float bflo(unsigned int v) { return __uint_as_float(v << 16); }
__device__ __forceinline__ float bfhi(unsigned int v) { return __uint_as_float(v & 0xffff0000u); }

// ---------------- atomic-free out-degree histogram (LDS-private, segmented) ----------------
__global__ __launch_bounds__(512) void k_hist(const int* __restrict__ src, int* __restrict__ partials,
                                              int N, int E) {
    __shared__ int h[HSEG];
    int per = (E + HB - 1) / HB;
    int e0 = blockIdx.x * per, e1 = min(e0 + per, E);
    for (int lo = 0; lo < N; lo += HSEG) {
        int hi = min(lo + HSEG, N);
        int len = hi - lo;
        for (int i = threadIdx.x; i < len; i += 512) h[i] = 0;
        __syncthreads();
        for (int e = e0 + threadIdx.x; e < e1; e += 512) {
            int s = src[e] - lo;
            if ((unsigned)s < (unsigned)len) atomicAdd(&h[s], 1);  // LDS atomic
        }
        __syncthreads();
        for (int i = threadIdx.x; i < len; i += 512)
            partials[(size_t)blockIdx.x * N + lo + i] = h[i];
        __syncthreads();
    }
}

__global__ __launch_bounds__(256) void k_hist_reduce(const int* __restrict__ partials,
                                                     float* __restrict__ doutv, int N) {
    int i = blockIdx.x * 256 + threadIdx.x;
    if (i >= N) return;
    int s = 0;
#pragma unroll
    for (int b = 0; b < HB; ++b) s += partials[(size_t)b * N + i];
    doutv[i] = s > 0 ? 1.0f / sqrtf((float)s) : 0.0f;
}

// ---------------- edge binning by dst bucket (atomic-free counting sort) ----------------
__global__ __launch_bounds__(256) void k_binA(const int* __restrict__ dst, int* __restrict__ counts,
                                              int nbuck, int E) {
    __shared__ int h[1024];
    for (int i = threadIdx.x; i < nbuck; i += 256) h[i] = 0;
    __syncthreads();
    int per = (E + NBLK - 1) / NBLK;
    int e0 = blockIdx.x * per, e1 = min(e0 + per, E);
    for (int e = e0 + threadIdx.x; e < e1; e += 256) atomicAdd(&h[dst[e] >> 6], 1);
    __syncthreads();
    for (int i = threadIdx.x; i < nbuck; i += 256) counts[(size_t)i * NBLK + blockIdx.x] = h[i];
}

__global__ __launch_bounds__(128) void k_binB1(const int* __restrict__ counts, int* __restrict__ tot) {
    __shared__ int sm[128];
    int t = threadIdx.x;
    sm[t] = counts[(size_t)blockIdx.x * NBLK + t];
    __syncthreads();
#pragma unroll
    for (int o = 64; o >= 1; o >>= 1) {
        if (t < o) sm[t] += sm[t + o];
        __syncthreads();
    }
    if (t == 0) tot[blockIdx.x] = sm[0];
}

__global__ __launch_bounds__(1024) void k_binB2(const int* __restrict__ tot, int* __restrict__ base,
                                                int nbuck, int E) {
    __shared__ int sm[1024];
    int t = threadIdx.x;
    int v = (t < nbuck) ? tot[t] : 0;
    sm[t] = v;
    __syncthreads();
    for (int o = 1; o < 1024; o <<= 1) {
        int u = (t >= o) ? sm[t - o] : 0;
        __syncthreads();
        sm[t] += u;
        __syncthreads();
    }
    if (t < nbuck) base[t] = sm[t] - v;  // exclusive
    if (t == 0) base[nbuck] = E;
}

__global__ __launch_bounds__(128) void k_binB3(const int* __restrict__ counts, const int* __restrict__ base,
                                               int* __restrict__ offs) {
    __shared__ int sm[128];
    int t = threadIdx.x;
    int v = counts[(size_t)blockIdx.x * NBLK + t];
    sm[t] = v;
    __syncthreads();
    for (int o = 1; o < 128; o <<= 1) {
        int u = (t >= o) ? sm[t - o] : 0;
        __syncthreads();
        sm[t] += u;
        __syncthreads();
    }
    offs[(size_t)blockIdx.x * NBLK + t] = base[blockIdx.x] + sm[t] - v;
}

__global__ __launch_bounds__(256) void k_binC(const int* __restrict__ src, const int* __restrict__ dst,
                                              const int* __restrict__ offs, uint2* __restrict__ binned,
                                              int nbuck, int E) {
    __shared__ int cur[1024];
    for (int i = threadIdx.x; i < nbuck; i += 256) cur[i] = offs[(size_t)i * NBLK + blockIdx.x];
    __syncthreads();
    int per = (E + NBLK - 1) / NBLK;
    int e0 = blockIdx.x * per, e1 = min(e0 + per, E);
    for (int e = e0 + threadIdx.x; e < e1; e += 256) {
        int d = dst[e];
        int p = atomicAdd(&cur[d >> 6], 1);  // LDS atomic
        binned[p] = make_uint2((unsigned)src[e], (unsigned)d);
    }
}

// ---------------- prep: mask+noise -> xs (bf16); feat copy; mask float (dout folded into GEMM) ----------------
__global__ __launch_bounds__(256) void k_prep(const float* __restrict__ feat, const float* __restrict__ noise,
                                              const int* __restrict__ mask, const float* __restrict__ token,
                                              unsigned short* __restrict__ xs, float* __restrict__ feat_out,
                                              float* __restrict__ mask_out, int n) {
    int i = blockIdx.x * blockDim.x + threadIdx.x;
    int total = n * 32;
    if (i >= total) return;
    int row = i >> 5, q = i & 31;
    float4 f = ((const float4*)feat)[i];
    float4 nz = ((const float4*)noise)[i];
    bool m = mask[row] != 0;
    float4 b = f;
    if (m) b = ((const float4*)token)[q];
    uint2 p;
    p.x = pack2bf(b.x + 0.1f * nz.x, b.y + 0.1f * nz.y);
    p.y = pack2bf(b.z + 0.1f * nz.z, b.w + 0.1f * nz.w);
    ((uint2*)xs)[i] = p;
    ((float4*)feat_out)[i] = f;
    if (q == 0) mask_out[row] = m ? 1.0f : 0.0f;
}

// ---------------- MFMA GEMM: C[n,128] = A_bf16[n,128] @ W_f32[128,128] (*dout[row])(+bias)(+relu) ----------------
template <int EPI, int OUT_BF16, int DOUT>
__global__ __launch_bounds__(256) void k_gemm_mfma(const unsigned short* __restrict__ A,
                                                   const float* __restrict__ W,
                                                   const float* __restrict__ bias,
                                                   const float* __restrict__ dscale,
                                                   void* __restrict__ Cout, int n) {
    __shared__ unsigned short Bt[128 * 136];  // Bt[c][k] = W[k][c], bf16, padded
    int tid = threadIdx.x;
    for (int idx = tid; idx < 128 * 128; idx += 256) {
        int k = idx >> 7, c = idx & 127;
        Bt[c * 136 + k] = f2bf(W[idx]);
    }
    __syncthreads();

    int wid = tid >> 6, lane = tid & 63;
    int q = lane >> 4, m = lane & 15;
    int r0 = blockIdx.x * 128 + wid * 32;

    f32x4 acc[2][8];
#pragma unroll
    for (int i = 0; i < 2; ++i)
#pragma unroll
        for (int j = 0; j < 8; ++j) acc[i][j] = (f32x4){0.f, 0.f, 0.f, 0.f};

#pragma unroll
    for (int ks = 0; ks < 4; ++ks) {
        int k0 = ks * 32 + q * 8;
        short8 a[2];
#pragma unroll
        for (int i = 0; i < 2; ++i) {
            int row = r0 + i * 16 + m;
            if (row > n - 1) row = n - 1;  // clamp; discarded at store
            a[i] = *(const short8*)(A + (size_t)row * 128 + k0);
        }
        short8 b[8];
#pragma unroll
        for (int j = 0; j < 8; ++j)
            b[j] = *(const short8*)(&Bt[(j * 16 + m) * 136 + k0]);
#pragma unroll
        for (int i = 0; i < 2; ++i)
#pragma unroll
            for (int j = 0; j < 8; ++j)
                acc[i][j] = __builtin_amdgcn_mfma_f32_16x16x32_bf16(a[i], b[j], acc[i][j], 0, 0, 0);
    }

    float bv[8];
    if (EPI >= 1) {
#pragma unroll
        for (int j = 0; j < 8; ++j) bv[j] = bias[j * 16 + m];
    }

#pragma unroll
    for (int i = 0; i < 2; ++i) {
#pragma unroll
        for (int r = 0; r < 4; ++r) {
            int row = r0 + i * 16 + q * 4 + r;
            if (row < n) {
                float ds = DOUT ? dscale[row] : 1.0f;
#pragma unroll
                for (int j = 0; j < 8; ++j) {
                    float v = acc[i][j][r];
                    if (DOUT) v *= ds;
                    if (EPI >= 1) v += bv[j];
                    if (EPI == 2) v = fmaxf(v, 0.0f);
                    if (OUT_BF16)
                        ((unsigned short*)Cout)[(size_t)row * 128 + j * 16 + m] = f2bf(v);
                    else
                        ((float*)Cout)[(size_t)row * 128 + j * 16 + m] = v;
                }
            }
        }
    }
}

// ---------------- per-bucket agg (LDS f32 acc) + bias + din scale + LN (+relu) ----------------
// MODE 1: out_bf = bf16( relu(LN(agg*din+cb)) )      (dout applied in next GEMM's epilogue)
// MODE 0: out_f32 = LN(agg*din+cb)  AND  out_bf = bf16(z)
template <int MODE>
__global__ __launch_bounds__(256) void k_agg_ln(const unsigned short* __restrict__ H,
                                                const uint2* __restrict__ binned,
                                                const int* __restrict__ base,
                                                const float* __restrict__ cb, const float* __restrict__ g,
                                                const float* __restrict__ bt,
                                                float* __restrict__ out_f32, unsigned short* __restrict__ out_bf,
                                                int n) {
    __shared__ float acc[BROWS * 128];
    __shared__ int cnt[BROWS];
    int tid = threadIdx.x, lane = tid & 63, wid = tid >> 6;
    for (int i = tid; i < BROWS * 32; i += 256) ((float4*)acc)[i] = (float4){0.f, 0.f, 0.f, 0.f};
    if (tid < BROWS) cnt[tid] = 0;
    __syncthreads();

    int b0 = base[blockIdx.x], b1 = base[blockIdx.x + 1];
    const unsigned int* Hu = (const unsigned int*)H;
    for (int eb = b0 + wid * 8; eb < b1; eb += 32) {
        int m = b1 - eb;
        if (m > 8) m = 8;
        unsigned int vals[8];
        int rows[8];
#pragma unroll
        for (int k = 0; k < 8; ++k) {
            if (k < m) {
                uint2 ed = binned[eb + k];
                rows[k] = (int)(ed.y & (BROWS - 1));
                vals[k] = Hu[(size_t)ed.x * 64 + lane];
            }
        }
#pragma unroll
        for (int k = 0; k < 8; ++k) {
            if (k < m) {
                atomicAdd(&acc[rows[k] * 128 + lane * 2], bflo(vals[k]));
                atomicAdd(&acc[rows[k] * 128 + lane * 2 + 1], bfhi(vals[k]));
                if (lane == 0) atomicAdd(&cnt[rows[k]], 1);
            }
        }
    }
    __syncthreads();

    for (int r = wid; r < BROWS; r += 4) {
        int gw = blockIdx.x * BROWS + r;
        if (gw >= n) break;
        int c = cnt[r];
        float sc = c > 0 ? 1.0f / sqrtf((float)c) : 0.0f;
        int d0 = lane * 2;
        float2 x = *(float2*)&acc[r * 128 + d0];
        float2 cbv = *(const float2*)(cb + d0);
        x.x = x.x * sc + cbv.x;
        x.y = x.y * sc + cbv.y;
        float s = x.x + x.y;
#pragma unroll
        for (int mm = 32; mm >= 1; mm >>= 1) s += __shfl_xor(s, mm, 64);
        float mu = s * (1.0f / 128.0f);
        float dx = x.x - mu, dy = x.y - mu;
        float v = dx * dx + dy * dy;
#pragma unroll
        for (int mm = 32; mm >= 1; mm >>= 1) v += __shfl_xor(v, mm, 64);
        float inv = 1.0f / sqrtf(v * (1.0f / 128.0f) + LN_EPS);
        float2 gv = *(const float2*)(g + d0);
        float2 bv = *(const float2*)(bt + d0);
        float y0 = dx * inv * gv.x + bv.x;
        float y1 = dy * inv * gv.y + bv.y;
        if (MODE == 1) {
            y0 = fmaxf(y0, 0.0f);
            y1 = fmaxf(y1, 0.0f);
        } else {
            *(float2*)(out_f32 + (size_t)gw * 128 + d0) = make_float2(y0, y1);
        }
        ((unsigned int*)out_bf)[(size_t)gw * 64 + lane] = pack2bf(y0, y1);
    }
}

// ---------------- classifier: logits[n,C] = Z_bf16 @ W + b ----------------
__global__ __launch_bounds__(256) void k_cls(const unsigned short* __restrict__ Z, const float* __restrict__ W,
                                             const float* __restrict__ b, float* __restrict__ out,
                                             int n, int C) {
    int gpos = blockIdx.x * blockDim.x + threadIdx.x;
    int row = gpos >> 4, c = gpos & 15;
    if (row >= n || c >= C) return;
    const unsigned int* zr = (const unsigned int*)(Z + (size_t)row * 128);
    float acc = b[c];
#pragma unroll 8
    for (int kk = 0; kk < 64; ++kk) {
        unsigned int v = zr[kk];
        acc = fmaf(bflo(v), W[(2 * kk) * C + c], acc);
        acc = fmaf(bfhi(v), W[(2 * kk + 1) * C + c], acc);
    }
    out[(size_t)row * C + c] = acc;
}

extern "C" void kernel_launch(void* const* d_in, const int* in_sizes, int n_in,
                              void* d_out, int out_size, void* d_ws, size_t ws_size,
                              hipStream_t stream) {
    const float* feat  = (const float*)d_in[0];
    const float* noise = (const float*)d_in[1];
    const int*   nmask = (const int*)d_in[2];
    const int*   src   = (const int*)d_in[3];
    const int*   dst   = (const int*)d_in[4];
    const float* token = (const float*)d_in[5];
    const float* W0    = (const float*)d_in[6];
    const float* b0    = (const float*)d_in[7];
    const float* ln0g  = (const float*)d_in[8];
    const float* ln0b  = (const float*)d_in[9];
    const float* W1    = (const float*)d_in[10];
    const float* b1    = (const float*)d_in[11];
    const float* ln1g  = (const float*)d_in[12];
    const float* ln1b  = (const float*)d_in[13];
    const float* dW1   = (const float*)d_in[14];
    const float* db1   = (const float*)d_in[15];
    const float* dW2   = (const float*)d_in[16];
    const float* db2   = (const float*)d_in[17];
    const float* cW    = (const float*)d_in[18];
    const float* cbias = (const float*)d_in[19];

    const int N = in_sizes[0] / 128;
    const int E = in_sizes[3];
    const int C = in_sizes[19];
    const size_t ND = (size_t)N * 128;
    const int NBUCK = (N + BROWS - 1) / BROWS;  // 782 for N=50000 (must be <= 1024)

    float* out       = (float*)d_out;
    float* out_recon = out;
    float* out_feat  = out + ND;
    float* out_mask  = out + 2 * ND;
    float* out_z     = out + 2 * ND + N;
    float* out_log   = out + 3 * ND + N;

    char* w = (char*)d_ws;
    unsigned short* bufX = (unsigned short*)w; w += ND * 2;   // bf16 ping
    unsigned short* bufH = (unsigned short*)w; w += ND * 2;   // bf16 pong
    unsigned short* zbf  = (unsigned short*)w; w += ND * 2;   // bf16 z
    float* doutv = (float*)w; w += (size_t)N * 4;
    int* scratch = (int*)w;  // union region: max(HB*N, bin structures) ints

    // phase-1 view: histogram partials (dead after k_hist_reduce)
    int* partials = scratch;
    // phase-2 view (same memory): binning structures
    int* counts = scratch;                                    // NBUCK*NBLK
    int* tot    = counts + (size_t)NBUCK * NBLK;              // NBUCK
    int* base   = tot + NBUCK;                                // NBUCK+1
    size_t boff = (size_t)NBUCK * NBLK + NBUCK + NBUCK + 2;
    int* offs   = scratch + boff;                             // NBUCK*NBLK
    size_t eoff = boff + (size_t)NBUCK * NBLK;
    if (eoff & 1) eoff++;                                     // 8B align for uint2
    uint2* binned = (uint2*)(scratch + eoff);                 // E entries

    int nb = (N + 255) / 256;

    // out-degree histogram (atomic-free) -> doutv
    k_hist<<<HB, 512, 0, stream>>>(src, partials, N, E);
    k_hist_reduce<<<nb, 256, 0, stream>>>(partials, doutv, N);

    // edge binning by dst bucket (atomic-free counting sort); reuses partials memory
    k_binA<<<NBLK, 256, 0, stream>>>(dst, counts, NBUCK, E);
    k_binB1<<<NBUCK, 128, 0, stream>>>(counts, tot);
    k_binB2<<<1, 1024, 0, stream>>>(tot, base, NBUCK, E);
    k_binB3<<<NBUCK, 128, 0, stream>>>(counts, base, offs);
    k_binC<<<NBLK, 256, 0, stream>>>(src, dst, offs, binned, NBUCK, E);

    k_prep<<<(N * 32 + 255) / 256, 256, 0, stream>>>(feat, noise, nmask, token,
                                                     bufX, out_feat, out_mask, N);

    int gb = (N + 127) / 128;

    // layer 0: H = (X@W0)*dout[row]; per-bucket agg + LN + relu
    k_gemm_mfma<0, 1, 1><<<gb, 256, 0, stream>>>(bufX, W0, nullptr, doutv, bufH, N);
    k_agg_ln<1><<<NBUCK, 256, 0, stream>>>(bufH, binned, base, b0, ln0g, ln0b, nullptr, bufX, N);

    // layer 1: H = (h@W1)*dout[row]; agg + LN -> z
    k_gemm_mfma<0, 1, 1><<<gb, 256, 0, stream>>>(bufX, W1, nullptr, doutv, bufH, N);
    k_agg_ln<0><<<NBUCK, 256, 0, stream>>>(bufH, binned, base, b1, ln1g, ln1b, out_z, zbf, N);

    // decoder
    k_gemm_mfma<2, 1, 0><<<gb, 256, 0, stream>>>(zbf, dW1, db1, nullptr, bufX, N);
    k_gemm_mfma<1, 0, 0><<<gb, 256, 0, stream>>>(bufX, dW2, db2, nullptr, out_recon, N);

    // classifier
    k_cls<<<(N * 16 + 255) / 256, 256, 0, stream>>>(zbf, cW, cbias, out_log, N, C);
}

// Round 6
// 267.024 us; speedup vs baseline: 5.8615x; 5.8615x over previous
//
#include <hip/hip_runtime.h>
#include <hip/hip_bf16.h>

#define LN_EPS 1e-5f
#define HB 64          // histogram blocks
#define HSEG 12800     // histogram LDS segment (51.2 KB)
#define NBLK 128       // binning blocks
#define BROWS 64       // rows per dst bucket

typedef __attribute__((ext_vector_type(8))) short short8;
typedef __attribute__((ext_vector_type(4))) float f32x4;

// ---- bf16 helpers (bit-level, RNE) ----
__device__ __forceinline__ unsigned short f2bf(float f) {
    unsigned int u = __float_as_uint(f);
    u += 0x7fffu + ((u >> 16) & 1u);
    return (unsigned short)(u >> 16);
}
__device__ __forceinline__ unsigned int pack2bf(float a, float b) {
    return (unsigned int)f2bf(a) | ((unsigned int)f2bf(b) << 16);
}
__device__ __forceinline__ float bflo(unsigned int v) { return __uint_as_float(v << 16); }
__device__ __forceinline__ float bfhi(unsigned int v) { return __uint_as_float(v & 0xffff0000u); }

// ---------------- atomic-free out-degree histogram (LDS-private, segmented) ----------------
__global__ __launch_bounds__(512) void k_hist(const int* __restrict__ src, int* __restrict__ partials,
                                              int N, int E) {
    __shared__ int h[HSEG];
    int per = (E + HB - 1) / HB;
    int e0 = blockIdx.x * per, e1 = min(e0 + per, E);
    for (int lo = 0; lo < N; lo += HSEG) {
        int hi = min(lo + HSEG, N);
        int len = hi - lo;
        for (int i = threadIdx.x; i < len; i += 512) h[i] = 0;
        __syncthreads();
        for (int e = e0 + threadIdx.x; e < e1; e += 512) {
            int s = src[e] - lo;
            if ((unsigned)s < (unsigned)len) atomicAdd(&h[s], 1);  // LDS atomic
        }
        __syncthreads();
        for (int i = threadIdx.x; i < len; i += 512)
            partials[(size_t)blockIdx.x * N + lo + i] = h[i];
        __syncthreads();
    }
}

__global__ __launch_bounds__(256) void k_hist_reduce(const int* __restrict__ partials,
                                                     float* __restrict__ doutv, int N) {
    int i = blockIdx.x * 256 + threadIdx.x;
    if (i >= N) return;
    int s = 0;
#pragma unroll
    for (int b = 0; b < HB; ++b) s += partials[(size_t)b * N + i];
    doutv[i] = s > 0 ? 1.0f / sqrtf((float)s) : 0.0f;
}

// ---------------- edge binning by dst bucket (atomic-free counting sort, LDS atomics only) ----------------
__global__ __launch_bounds__(256) void k_binA(const int* __restrict__ dst, int* __restrict__ counts,
                                              int nbuck, int E) {
    __shared__ int h[1024];
    for (int i = threadIdx.x; i < nbuck; i += 256) h[i] = 0;
    __syncthreads();
    int per = (E + NBLK - 1) / NBLK;
    int e0 = blockIdx.x * per, e1 = min(e0 + per, E);
    for (int e = e0 + threadIdx.x; e < e1; e += 256) atomicAdd(&h[dst[e] >> 6], 1);
    __syncthreads();
    for (int i = threadIdx.x; i < nbuck; i += 256) counts[(size_t)i * NBLK + blockIdx.x] = h[i];
}

__global__ __launch_bounds__(128) void k_binB1(const int* __restrict__ counts, int* __restrict__ tot) {
    __shared__ int sm[128];
    int t = threadIdx.x;
    sm[t] = counts[(size_t)blockIdx.x * NBLK + t];
    __syncthreads();
#pragma unroll
    for (int o = 64; o >= 1; o >>= 1) {
        if (t < o) sm[t] += sm[t + o];
        __syncthreads();
    }
    if (t == 0) tot[blockIdx.x] = sm[0];
}

__global__ __launch_bounds__(1024) void k_binB2(const int* __restrict__ tot, int* __restrict__ base,
                                                int nbuck, int E) {
    __shared__ int sm[1024];
    int t = threadIdx.x;
    int v = (t < nbuck) ? tot[t] : 0;
    sm[t] = v;
    __syncthreads();
    for (int o = 1; o < 1024; o <<= 1) {
        int u = (t >= o) ? sm[t - o] : 0;
        __syncthreads();
        sm[t] += u;
        __syncthreads();
    }
    if (t < nbuck) base[t] = sm[t] - v;  // exclusive
    if (t == 0) base[nbuck] = E;
}

__global__ __launch_bounds__(128) void k_binB3(const int* __restrict__ counts, const int* __restrict__ base,
                                               int* __restrict__ offs) {
    __shared__ int sm[128];
    int t = threadIdx.x;
    int v = counts[(size_t)blockIdx.x * NBLK + t];
    sm[t] = v;
    __syncthreads();
    for (int o = 1; o < 128; o <<= 1) {
        int u = (t >= o) ? sm[t - o] : 0;
        __syncthreads();
        sm[t] += u;
        __syncthreads();
    }
    offs[(size_t)blockIdx.x * NBLK + t] = base[blockIdx.x] + sm[t] - v;
}

__global__ __launch_bounds__(256) void k_binC(const int* __restrict__ src, const int* __restrict__ dst,
                                              const int* __restrict__ offs, uint2* __restrict__ binned,
                                              int nbuck, int E) {
    __shared__ int cur[1024];
    for (int i = threadIdx.x; i < nbuck; i += 256) cur[i] = offs[(size_t)i * NBLK + blockIdx.x];
    __syncthreads();
    int per = (E + NBLK - 1) / NBLK;
    int e0 = blockIdx.x * per, e1 = min(e0 + per, E);
    for (int e = e0 + threadIdx.x; e < e1; e += 256) {
        int d = dst[e];
        int p = atomicAdd(&cur[d >> 6], 1);  // LDS atomic
        binned[p] = make_uint2((unsigned)src[e], (unsigned)d);
    }
}

// ---------------- per-bucket CSR build (LDS atomics only): row_ptr + csr_src ----------------
__global__ __launch_bounds__(256) void k_csr(const uint2* __restrict__ binned, const int* __restrict__ base,
                                             int* __restrict__ row_ptr, int* __restrict__ csr_src, int N) {
    __shared__ int hcnt[BROWS], hoff[BROWS], ccur[BROWS];
    int b = blockIdx.x, t = threadIdx.x;
    int e0 = base[b], e1 = base[b + 1];
    if (t < BROWS) hcnt[t] = 0;
    __syncthreads();
    for (int e = e0 + t; e < e1; e += 256)
        atomicAdd(&hcnt[binned[e].y & (BROWS - 1)], 1);
    __syncthreads();
    if (t < BROWS) {
        int acc = 0;
        for (int r = 0; r < t; ++r) acc += hcnt[r];
        hoff[t] = acc;
        ccur[t] = acc;
        int gw = b * BROWS + t;
        if (gw <= N) row_ptr[gw] = e0 + acc;   // last bucket's overhang writes row_ptr[N]
    }
    __syncthreads();
    for (int e = e0 + t; e < e1; e += 256) {
        uint2 ed = binned[e];
        int p = atomicAdd(&ccur[ed.y & (BROWS - 1)], 1);
        csr_src[e0 + p] = (int)ed.x;
    }
}

// ---------------- prep: mask+noise -> xs (bf16); feat copy; mask float (dout folded into GEMM) ----------------
__global__ __launch_bounds__(256) void k_prep(const float* __restrict__ feat, const float* __restrict__ noise,
                                              const int* __restrict__ mask, const float* __restrict__ token,
                                              unsigned short* __restrict__ xs, float* __restrict__ feat_out,
                                              float* __restrict__ mask_out, int n) {
    int i = blockIdx.x * blockDim.x + threadIdx.x;
    int total = n * 32;
    if (i >= total) return;
    int row = i >> 5, q = i & 31;
    float4 f = ((const float4*)feat)[i];
    float4 nz = ((const float4*)noise)[i];
    bool m = mask[row] != 0;
    float4 b = f;
    if (m) b = ((const float4*)token)[q];
    uint2 p;
    p.x = pack2bf(b.x + 0.1f * nz.x, b.y + 0.1f * nz.y);
    p.y = pack2bf(b.z + 0.1f * nz.z, b.w + 0.1f * nz.w);
    ((uint2*)xs)[i] = p;
    ((float4*)feat_out)[i] = f;
    if (q == 0) mask_out[row] = m ? 1.0f : 0.0f;
}

// ---------------- MFMA GEMM: C[n,128] = A_bf16[n,128] @ W_f32[128,128] (*dout[row])(+bias)(+relu) ----------------
template <int EPI, int OUT_BF16, int DOUT>
__global__ __launch_bounds__(256) void k_gemm_mfma(const unsigned short* __restrict__ A,
                                                   const float* __restrict__ W,
                                                   const float* __restrict__ bias,
                                                   const float* __restrict__ dscale,
                                                   void* __restrict__ Cout, int n) {
    __shared__ unsigned short Bt[128 * 136];  // Bt[c][k] = W[k][c], bf16, padded
    int tid = threadIdx.x;
    for (int i4 = tid; i4 < 128 * 32; i4 += 256) {
        int k = i4 >> 5, c = (i4 & 31) * 4;
        float4 wv = *(const float4*)(W + k * 128 + c);
        Bt[(c + 0) * 136 + k] = f2bf(wv.x);
        Bt[(c + 1) * 136 + k] = f2bf(wv.y);
        Bt[(c + 2) * 136 + k] = f2bf(wv.z);
        Bt[(c + 3) * 136 + k] = f2bf(wv.w);
    }
    __syncthreads();

    int wid = tid >> 6, lane = tid & 63;
    int q = lane >> 4, m = lane & 15;
    int r0 = blockIdx.x * 128 + wid * 32;

    f32x4 acc[2][8];
#pragma unroll
    for (int i = 0; i < 2; ++i)
#pragma unroll
        for (int j = 0; j < 8; ++j) acc[i][j] = (f32x4){0.f, 0.f, 0.f, 0.f};

#pragma unroll
    for (int ks = 0; ks < 4; ++ks) {
        int k0 = ks * 32 + q * 8;
        short8 a[2];
#pragma unroll
        for (int i = 0; i < 2; ++i) {
            int row = r0 + i * 16 + m;
            if (row > n - 1) row = n - 1;  // clamp; discarded at store
            a[i] = *(const short8*)(A + (size_t)row * 128 + k0);
        }
        short8 b[8];
#pragma unroll
        for (int j = 0; j < 8; ++j)
            b[j] = *(const short8*)(&Bt[(j * 16 + m) * 136 + k0]);
#pragma unroll
        for (int i = 0; i < 2; ++i)
#pragma unroll
            for (int j = 0; j < 8; ++j)
                acc[i][j] = __builtin_amdgcn_mfma_f32_16x16x32_bf16(a[i], b[j], acc[i][j], 0, 0, 0);
    }

    float bv[8];
    if (EPI >= 1) {
#pragma unroll
        for (int j = 0; j < 8; ++j) bv[j] = bias[j * 16 + m];
    }

#pragma unroll
    for (int i = 0; i < 2; ++i) {
#pragma unroll
        for (int r = 0; r < 4; ++r) {
            int row = r0 + i * 16 + q * 4 + r;
            if (row < n) {
                float ds = DOUT ? dscale[row] : 1.0f;
#pragma unroll
                for (int j = 0; j < 8; ++j) {
                    float v = acc[i][j][r];
                    if (DOUT) v *= ds;
                    if (EPI >= 1) v += bv[j];
                    if (EPI == 2) v = fmaxf(v, 0.0f);
                    if (OUT_BF16)
                        ((unsigned short*)Cout)[(size_t)row * 128 + j * 16 + m] = f2bf(v);
                    else
                        ((float*)Cout)[(size_t)row * 128 + j * 16 + m] = v;
                }
            }
        }
    }
}

// ---------------- fused CSR agg (bf16 gather, wave per row) + bias + din scale + LN (+relu) ----------------
// MODE 1: out_bf = bf16( relu(LN(agg*din+cb)) )      (dout applied in next GEMM's epilogue)
// MODE 0: out_f32 = LN(agg*din+cb)  AND  out_bf = bf16(z)
template <int MODE>
__global__ __launch_bounds__(256) void k_agg_ln(const unsigned short* __restrict__ H,
                                                const int* __restrict__ row_ptr,
                                                const int* __restrict__ csr_src,
                                                const float* __restrict__ cb, const float* __restrict__ g,
                                                const float* __restrict__ bt,
                                                float* __restrict__ out_f32, unsigned short* __restrict__ out_bf,
                                                int n) {
    int gw = (blockIdx.x * blockDim.x + threadIdx.x) >> 6;
    int lane = threadIdx.x & 63;
    if (gw >= n) return;
    int beg = row_ptr[gw], end = row_ptr[gw + 1];
    int cnt = end - beg;
    const unsigned int* Hu = (const unsigned int*)H;
    float ax0 = 0.f, ay0 = 0.f, ax1 = 0.f, ay1 = 0.f;
    float ax2 = 0.f, ay2 = 0.f, ax3 = 0.f, ay3 = 0.f;
    int j = beg;
    for (; j + 3 < end; j += 4) {
        int s0 = csr_src[j], s1 = csr_src[j + 1], s2 = csr_src[j + 2], s3 = csr_src[j + 3];
        unsigned int v0 = Hu[(size_t)s0 * 64 + lane];
        unsigned int v1 = Hu[(size_t)s1 * 64 + lane];
        unsigned int v2 = Hu[(size_t)s2 * 64 + lane];
        unsigned int v3 = Hu[(size_t)s3 * 64 + lane];
        ax0 += bflo(v0); ay0 += bfhi(v0);
        ax1 += bflo(v1); ay1 += bfhi(v1);
        ax2 += bflo(v2); ay2 += bfhi(v2);
        ax3 += bflo(v3); ay3 += bfhi(v3);
    }
    for (; j < end; ++j) {
        int s0 = csr_src[j];
        unsigned int v0 = Hu[(size_t)s0 * 64 + lane];
        ax0 += bflo(v0); ay0 += bfhi(v0);
    }
    int d0 = lane * 2;
    float sc = cnt > 0 ? 1.0f / sqrtf((float)cnt) : 0.0f;
    float2 cbv = *(const float2*)(cb + d0);
    float2 x;
    x.x = (ax0 + ax1 + ax2 + ax3) * sc + cbv.x;
    x.y = (ay0 + ay1 + ay2 + ay3) * sc + cbv.y;

    float s = x.x + x.y;
#pragma unroll
    for (int mm = 32; mm >= 1; mm >>= 1) s += __shfl_xor(s, mm, 64);
    float mu = s * (1.0f / 128.0f);
    float dx = x.x - mu, dy = x.y - mu;
    float v = dx * dx + dy * dy;
#pragma unroll
    for (int mm = 32; mm >= 1; mm >>= 1) v += __shfl_xor(v, mm, 64);
    float inv = 1.0f / sqrtf(v * (1.0f / 128.0f) + LN_EPS);
    float2 gv = *(const float2*)(g + d0);
    float2 bv = *(const float2*)(bt + d0);
    float y0 = dx * inv * gv.x + bv.x;
    float y1 = dy * inv * gv.y + bv.y;
    if (MODE == 1) {
        y0 = fmaxf(y0, 0.0f);
        y1 = fmaxf(y1, 0.0f);
    } else {
        *(float2*)(out_f32 + (size_t)gw * 128 + d0) = make_float2(y0, y1);
    }
    ((unsigned int*)out_bf)[(size_t)gw * 64 + lane] = pack2bf(y0, y1);
}

// ---------------- classifier: logits[n,C] = Z_bf16 @ W + b ----------------
__global__ __launch_bounds__(256) void k_cls(const unsigned short* __restrict__ Z, const float* __restrict__ W,
                                             const float* __restrict__ b, float* __restrict__ out,
                                             int n, int C) {
    int gpos = blockIdx.x * blockDim.x + threadIdx.x;
    int row = gpos >> 4, c = gpos & 15;
    if (row >= n || c >= C) return;
    const unsigned int* zr = (const unsigned int*)(Z + (size_t)row * 128);
    float acc = b[c];
#pragma unroll 8
    for (int kk = 0; kk < 64; ++kk) {
        unsigned int v = zr[kk];
        acc = fmaf(bflo(v), W[(2 * kk) * C + c], acc);
        acc = fmaf(bfhi(v), W[(2 * kk + 1) * C + c], acc);
    }
    out[(size_t)row * C + c] = acc;
}

extern "C" void kernel_launch(void* const* d_in, const int* in_sizes, int n_in,
                              void* d_out, int out_size, void* d_ws, size_t ws_size,
                              hipStream_t stream) {
    const float* feat  = (const float*)d_in[0];
    const float* noise = (const float*)d_in[1];
    const int*   nmask = (const int*)d_in[2];
    const int*   src   = (const int*)d_in[3];
    const int*   dst   = (const int*)d_in[4];
    const float* token = (const float*)d_in[5];
    const float* W0    = (const float*)d_in[6];
    const float* b0    = (const float*)d_in[7];
    const float* ln0g  = (const float*)d_in[8];
    const float* ln0b  = (const float*)d_in[9];
    const float* W1    = (const float*)d_in[10];
    const float* b1    = (const float*)d_in[11];
    const float* ln1g  = (const float*)d_in[12];
    const float* ln1b  = (const float*)d_in[13];
    const float* dW1   = (const float*)d_in[14];
    const float* db1   = (const float*)d_in[15];
    const float* dW2   = (const float*)d_in[16];
    const float* db2   = (const float*)d_in[17];
    const float* cW    = (const float*)d_in[18];
    const float* cbias = (const float*)d_in[19];

    const int N = in_sizes[0] / 128;
    const int E = in_sizes[3];
    const int C = in_sizes[19];
    const size_t ND = (size_t)N * 128;
    const int NBUCK = (N + BROWS - 1) / BROWS;  // 782 for N=50000 (<= 1024)

    float* out       = (float*)d_out;
    float* out_recon = out;
    float* out_feat  = out + ND;
    float* out_mask  = out + 2 * ND;
    float* out_z     = out + 2 * ND + N;
    float* out_log   = out + 3 * ND + N;

    char* w = (char*)d_ws;
    unsigned short* bufX = (unsigned short*)w; w += ND * 2;   // bf16 ping
    unsigned short* bufH = (unsigned short*)w; w += ND * 2;   // bf16 pong
    unsigned short* zbf  = (unsigned short*)w; w += ND * 2;   // bf16 z
    float* doutv   = (float*)w; w += (size_t)N * 4;
    int* row_ptr   = (int*)w;   w += (size_t)(N + 4) * 4;
    int* csr_src   = (int*)w;   w += (size_t)E * 4;
    int* scratch   = (int*)w;   // union: HB*N hist partials, then binning structures

    // phase-1 view
    int* partials = scratch;
    // phase-2 view (sequential on stream; partials dead by then)
    uint2* binned = (uint2*)scratch;                          // E entries (8B-aligned)
    int* counts = scratch + (size_t)2 * E;                    // NBUCK*NBLK
    int* tot    = counts + (size_t)NBUCK * NBLK;              // NBUCK
    int* base   = tot + NBUCK;                                // NBUCK+1
    int* offs   = base + NBUCK + 2;                           // NBUCK*NBLK

    int nb = (N + 255) / 256;

    // out-degree (atomic-free) -> doutv
    k_hist<<<HB, 512, 0, stream>>>(src, partials, N, E);
    k_hist_reduce<<<nb, 256, 0, stream>>>(partials, doutv, N);

    // dst-bucket counting sort (LDS atomics only)
    k_binA<<<NBLK, 256, 0, stream>>>(dst, counts, NBUCK, E);
    k_binB1<<<NBUCK, 128, 0, stream>>>(counts, tot);
    k_binB2<<<1, 1024, 0, stream>>>(tot, base, NBUCK, E);
    k_binB3<<<NBUCK, 128, 0, stream>>>(counts, base, offs);
    k_binC<<<NBLK, 256, 0, stream>>>(src, dst, offs, binned, NBUCK, E);
    // per-bucket CSR finalize
    k_csr<<<NBUCK, 256, 0, stream>>>(binned, base, row_ptr, csr_src, N);

    k_prep<<<(N * 32 + 255) / 256, 256, 0, stream>>>(feat, noise, nmask, token,
                                                     bufX, out_feat, out_mask, N);

    int gb = (N + 127) / 128;
    int rb = (N * 64 + 255) / 256;

    // layer 0: H = (X@W0)*dout[row]; wave-per-row agg + LN + relu
    k_gemm_mfma<0, 1, 1><<<gb, 256, 0, stream>>>(bufX, W0, nullptr, doutv, bufH, N);
    k_agg_ln<1><<<rb, 256, 0, stream>>>(bufH, row_ptr, csr_src, b0, ln0g, ln0b, nullptr, bufX, N);

    // layer 1: H = (h@W1)*dout[row]; agg + LN -> z
    k_gemm_mfma<0, 1, 1><<<gb, 256, 0, stream>>>(bufX, W1, nullptr, doutv, bufH, N);
    k_agg_ln<0><<<rb, 256, 0, stream>>>(bufH, row_ptr, csr_src, b1, ln1g, ln1b, out_z, zbf, N);

    // decoder
    k_gemm_mfma<2, 1, 0><<<gb, 256, 0, stream>>>(zbf, dW1, db1, nullptr, bufX, N);
    k_gemm_mfma<1, 0, 0><<<gb, 256, 0, stream>>>(bufX, dW2, db2, nullptr, out_recon, N);

    // classifier
    k_cls<<<(N * 16 + 255) / 256, 256, 0, stream>>>(zbf, cW, cbias, out_log, N, C);
}

// Round 7
// 250.220 us; speedup vs baseline: 6.2552x; 1.0672x over previous
//
#include <hip/hip_runtime.h>
#include <hip/hip_bf16.h>

#define LN_EPS 1e-5f
#define HB 32          // histogram blocks
#define HSEG 12800     // histogram LDS segment (51.2 KB)
#define NBLK 128       // binning blocks
#define BROWS 64       // rows per dst bucket
#define WPSTRIDE 17408 // 128*136 shorts per packed weight

typedef __attribute__((ext_vector_type(8))) short short8;
typedef __attribute__((ext_vector_type(4))) float f32x4;

// ---- bf16 helpers (bit-level, RNE) ----
__device__ __forceinline__ unsigned short f2bf(float f) {
    unsigned int u = __float_as_uint(f);
    u += 0x7fffu + ((u >> 16) & 1u);
    return (unsigned short)(u >> 16);
}
__device__ __forceinline__ unsigned int pack2bf(float a, float b) {
    return (unsigned int)f2bf(a) | ((unsigned int)f2bf(b) << 16);
}
__device__ __forceinline__ float bflo(unsigned int v) { return __uint_as_float(v << 16); }
__device__ __forceinline__ float bfhi(unsigned int v) { return __uint_as_float(v & 0xffff0000u); }

// ---------------- weight pre-pack: W[k][c] f32 -> Wp[c*136+k] bf16 (4 weights) ----------------
__global__ __launch_bounds__(256) void k_pack(const float* __restrict__ Wa, const float* __restrict__ Wb,
                                              const float* __restrict__ Wc, const float* __restrict__ Wd,
                                              unsigned short* __restrict__ dst) {
    int wsel = blockIdx.x >> 6;
    int idx = (blockIdx.x & 63) * 256 + threadIdx.x;   // 0..16383
    const float* W = wsel == 0 ? Wa : wsel == 1 ? Wb : wsel == 2 ? Wc : Wd;
    int c = idx >> 7, kk = idx & 127;
    dst[(size_t)wsel * WPSTRIDE + c * 136 + kk] = f2bf(W[kk * 128 + c]);
}

// ---------------- atomic-free out-degree histogram (LDS-private, segmented) ----------------
__global__ __launch_bounds__(512) void k_hist(const int* __restrict__ src, int* __restrict__ partials,
                                              int N, int E) {
    __shared__ int h[HSEG];
    int per = (E + HB - 1) / HB;
    int e0 = blockIdx.x * per, e1 = min(e0 + per, E);
    for (int lo = 0; lo < N; lo += HSEG) {
        int hi = min(lo + HSEG, N);
        int len = hi - lo;
        for (int i = threadIdx.x; i < len; i += 512) h[i] = 0;
        __syncthreads();
        for (int e = e0 + threadIdx.x; e < e1; e += 512) {
            int s = src[e] - lo;
            if ((unsigned)s < (unsigned)len) atomicAdd(&h[s], 1);  // LDS atomic
        }
        __syncthreads();
        for (int i = threadIdx.x; i < len; i += 512)
            partials[(size_t)blockIdx.x * N + lo + i] = h[i];
        __syncthreads();
    }
}

__global__ __launch_bounds__(256) void k_hist_reduce(const int* __restrict__ partials,
                                                     float* __restrict__ doutv, int N) {
    int i = blockIdx.x * 256 + threadIdx.x;
    if (i >= N) return;
    int s = 0;
#pragma unroll
    for (int b = 0; b < HB; ++b) s += partials[(size_t)b * N + i];
    doutv[i] = s > 0 ? 1.0f / sqrtf((float)s) : 0.0f;
}

// ---------------- edge binning by dst bucket (counting sort, LDS atomics only) ----------------
__global__ __launch_bounds__(256) void k_binA(const int* __restrict__ dst, int* __restrict__ counts,
                                              int nbuck, int E) {
    __shared__ int h[1024];
    for (int i = threadIdx.x; i < nbuck; i += 256) h[i] = 0;
    __syncthreads();
    int per = (E + NBLK - 1) / NBLK;
    int e0 = blockIdx.x * per, e1 = min(e0 + per, E);
    for (int e = e0 + threadIdx.x; e < e1; e += 256) atomicAdd(&h[dst[e] >> 6], 1);
    __syncthreads();
    for (int i = threadIdx.x; i < nbuck; i += 256) counts[(size_t)i * NBLK + blockIdx.x] = h[i];
}

__global__ __launch_bounds__(128) void k_binB1(const int* __restrict__ counts, int* __restrict__ tot) {
    __shared__ int sm[128];
    int t = threadIdx.x;
    sm[t] = counts[(size_t)blockIdx.x * NBLK + t];
    __syncthreads();
#pragma unroll
    for (int o = 64; o >= 1; o >>= 1) {
        if (t < o) sm[t] += sm[t + o];
        __syncthreads();
    }
    if (t == 0) tot[blockIdx.x] = sm[0];
}

__global__ __launch_bounds__(1024) void k_binB2(const int* __restrict__ tot, int* __restrict__ base,
                                                int nbuck, int E) {
    __shared__ int sm[1024];
    int t = threadIdx.x;
    int v = (t < nbuck) ? tot[t] : 0;
    sm[t] = v;
    __syncthreads();
    for (int o = 1; o < 1024; o <<= 1) {
        int u = (t >= o) ? sm[t - o] : 0;
        __syncthreads();
        sm[t] += u;
        __syncthreads();
    }
    if (t < nbuck) base[t] = sm[t] - v;  // exclusive
    if (t == 0) base[nbuck] = E;
}

__global__ __launch_bounds__(128) void k_binB3(const int* __restrict__ counts, const int* __restrict__ base,
                                               int* __restrict__ offs) {
    __shared__ int sm[128];
    int t = threadIdx.x;
    int v = counts[(size_t)blockIdx.x * NBLK + t];
    sm[t] = v;
    __syncthreads();
    for (int o = 1; o < 128; o <<= 1) {
        int u = (t >= o) ? sm[t - o] : 0;
        __syncthreads();
        sm[t] += u;
        __syncthreads();
    }
    offs[(size_t)blockIdx.x * NBLK + t] = base[blockIdx.x] + sm[t] - v;
}

__global__ __launch_bounds__(256) void k_binC(const int* __restrict__ src, const int* __restrict__ dst,
                                              const int* __restrict__ offs, uint2* __restrict__ binned,
                                              int nbuck, int E) {
    __shared__ int cur[1024];
    for (int i = threadIdx.x; i < nbuck; i += 256) cur[i] = offs[(size_t)i * NBLK + blockIdx.x];
    __syncthreads();
    int per = (E + NBLK - 1) / NBLK;
    int e0 = blockIdx.x * per, e1 = min(e0 + per, E);
    for (int e = e0 + threadIdx.x; e < e1; e += 256) {
        int d = dst[e];
        int p = atomicAdd(&cur[d >> 6], 1);  // LDS atomic
        binned[p] = make_uint2((unsigned)src[e], (unsigned)d);
    }
}

// ---------------- per-bucket CSR build (LDS atomics only): row_ptr + csr_src ----------------
__global__ __launch_bounds__(256) void k_csr(const uint2* __restrict__ binned, const int* __restrict__ base,
                                             int* __restrict__ row_ptr, int* __restrict__ csr_src, int N) {
    __shared__ int hcnt[BROWS], ccur[BROWS];
    int b = blockIdx.x, t = threadIdx.x;
    int e0 = base[b], e1 = base[b + 1];
    if (t < BROWS) hcnt[t] = 0;
    __syncthreads();
    for (int e = e0 + t; e < e1; e += 256)
        atomicAdd(&hcnt[binned[e].y & (BROWS - 1)], 1);
    __syncthreads();
    if (t < BROWS) {
        int acc = 0;
        for (int r = 0; r < t; ++r) acc += hcnt[r];
        ccur[t] = acc;
        int gw = b * BROWS + t;
        if (gw <= N) row_ptr[gw] = e0 + acc;   // last bucket's overhang writes row_ptr[N]
    }
    __syncthreads();
    for (int e = e0 + t; e < e1; e += 256) {
        uint2 ed = binned[e];
        int p = atomicAdd(&ccur[ed.y & (BROWS - 1)], 1);
        csr_src[e0 + p] = (int)ed.x;
    }
}

// ---------------- prep: mask+noise -> xs (bf16); feat copy; mask float ----------------
__global__ __launch_bounds__(256) void k_prep(const float* __restrict__ feat, const float* __restrict__ noise,
                                              const int* __restrict__ mask, const float* __restrict__ token,
                                              unsigned short* __restrict__ xs, float* __restrict__ feat_out,
                                              float* __restrict__ mask_out, int n) {
    int i = blockIdx.x * blockDim.x + threadIdx.x;
    int total = n * 32;
    if (i >= total) return;
    int row = i >> 5, q = i & 31;
    float4 f = ((const float4*)feat)[i];
    float4 nz = ((const float4*)noise)[i];
    bool m = mask[row] != 0;
    float4 b = f;
    if (m) b = ((const float4*)token)[q];
    uint2 p;
    p.x = pack2bf(b.x + 0.1f * nz.x, b.y + 0.1f * nz.y);
    p.y = pack2bf(b.z + 0.1f * nz.z, b.w + 0.1f * nz.w);
    ((uint2*)xs)[i] = p;
    ((float4*)feat_out)[i] = f;
    if (q == 0) mask_out[row] = m ? 1.0f : 0.0f;
}

// ---------------- MFMA GEMM with pre-packed bf16 weights ----------------
// C[n,128] = A_bf16[n,128] @ Wp (*dout[row])(+bias)(+relu)
template <int EPI, int OUT_BF16, int DOUT>
__global__ __launch_bounds__(256) void k_gemm_mfma(const unsigned short* __restrict__ A,
                                                   const unsigned short* __restrict__ Wp,
                                                   const float* __restrict__ bias,
                                                   const float* __restrict__ dscale,
                                                   void* __restrict__ Cout, int n) {
    __shared__ uint4 BtV[2176];  // 128*136 bf16 = 34816 B
    unsigned short* Bt = (unsigned short*)BtV;
    int tid = threadIdx.x;
    const uint4* Wv = (const uint4*)Wp;
    for (int i = tid; i < 2176; i += 256) BtV[i] = Wv[i];
    __syncthreads();

    int wid = tid >> 6, lane = tid & 63;
    int q = lane >> 4, m = lane & 15;
    int r0 = blockIdx.x * 128 + wid * 32;

    f32x4 acc[2][8];
#pragma unroll
    for (int i = 0; i < 2; ++i)
#pragma unroll
        for (int j = 0; j < 8; ++j) acc[i][j] = (f32x4){0.f, 0.f, 0.f, 0.f};

#pragma unroll
    for (int ks = 0; ks < 4; ++ks) {
        int k0 = ks * 32 + q * 8;
        short8 a[2];
#pragma unroll
        for (int i = 0; i < 2; ++i) {
            int row = r0 + i * 16 + m;
            if (row > n - 1) row = n - 1;  // clamp; discarded at store
            a[i] = *(const short8*)(A + (size_t)row * 128 + k0);
        }
        short8 b[8];
#pragma unroll
        for (int j = 0; j < 8; ++j)
            b[j] = *(const short8*)(&Bt[(j * 16 + m) * 136 + k0]);
#pragma unroll
        for (int i = 0; i < 2; ++i)
#pragma unroll
            for (int j = 0; j < 8; ++j)
                acc[i][j] = __builtin_amdgcn_mfma_f32_16x16x32_bf16(a[i], b[j], acc[i][j], 0, 0, 0);
    }

    float bv[8];
    if (EPI >= 1) {
#pragma unroll
        for (int j = 0; j < 8; ++j) bv[j] = bias[j * 16 + m];
    }

#pragma unroll
    for (int i = 0; i < 2; ++i) {
#pragma unroll
        for (int r = 0; r < 4; ++r) {
            int row = r0 + i * 16 + q * 4 + r;
            if (row < n) {
                float ds = DOUT ? dscale[row] : 1.0f;
#pragma unroll
                for (int j = 0; j < 8; ++j) {
                    float v = acc[i][j][r];
                    if (DOUT) v *= ds;
                    if (EPI >= 1) v += bv[j];
                    if (EPI == 2) v = fmaxf(v, 0.0f);
                    if (OUT_BF16)
                        ((unsigned short*)Cout)[(size_t)row * 128 + j * 16 + m] = f2bf(v);
                    else
                        ((float*)Cout)[(size_t)row * 128 + j * 16 + m] = v;
                }
            }
        }
    }
}

// ---------------- fused CSR agg (lane-parallel indices, 8-deep gather) + LN (+relu) ----------------
// MODE 1: out_bf = bf16( relu(LN(agg*din+cb)) )
// MODE 0: out_f32 = LN(agg*din+cb)  AND  out_bf = bf16(z)
template <int MODE>
__global__ __launch_bounds__(256) void k_agg_ln(const unsigned short* __restrict__ H,
                                                const int* __restrict__ row_ptr,
                                                const int* __restrict__ csr_src,
                                                const float* __restrict__ cb, const float* __restrict__ g,
                                                const float* __restrict__ bt,
                                                float* __restrict__ out_f32, unsigned short* __restrict__ out_bf,
                                                int n) {
    int gw = (blockIdx.x * blockDim.x + threadIdx.x) >> 6;
    int lane = threadIdx.x & 63;
    if (gw >= n) return;
    int beg = row_ptr[gw], end = row_ptr[gw + 1];
    int cnt = end - beg;
    const unsigned int* Hu = (const unsigned int*)H;
    float ax0 = 0.f, ay0 = 0.f, ax1 = 0.f, ay1 = 0.f;
    float ax2 = 0.f, ay2 = 0.f, ax3 = 0.f, ay3 = 0.f;
    for (int c0 = beg; c0 < end; c0 += 64) {
        int m = end - c0;
        if (m > 64) m = 64;
        int myidx = (lane < m) ? csr_src[c0 + lane] : 0;  // one coalesced index load per 64 edges
        int k = 0;
        for (; k + 7 < m; k += 8) {
            int s0 = __shfl(myidx, k + 0), s1 = __shfl(myidx, k + 1);
            int s2 = __shfl(myidx, k + 2), s3 = __shfl(myidx, k + 3);
            int s4 = __shfl(myidx, k + 4), s5 = __shfl(myidx, k + 5);
            int s6 = __shfl(myidx, k + 6), s7 = __shfl(myidx, k + 7);
            unsigned int v0 = Hu[(size_t)s0 * 64 + lane];
            unsigned int v1 = Hu[(size_t)s1 * 64 + lane];
            unsigned int v2 = Hu[(size_t)s2 * 64 + lane];
            unsigned int v3 = Hu[(size_t)s3 * 64 + lane];
            unsigned int v4 = Hu[(size_t)s4 * 64 + lane];
            unsigned int v5 = Hu[(size_t)s5 * 64 + lane];
            unsigned int v6 = Hu[(size_t)s6 * 64 + lane];
            unsigned int v7 = Hu[(size_t)s7 * 64 + lane];
            ax0 += bflo(v0); ay0 += bfhi(v0);
            ax1 += bflo(v1); ay1 += bfhi(v1);
            ax2 += bflo(v2); ay2 += bfhi(v2);
            ax3 += bflo(v3); ay3 += bfhi(v3);
            ax0 += bflo(v4); ay0 += bfhi(v4);
            ax1 += bflo(v5); ay1 += bfhi(v5);
            ax2 += bflo(v6); ay2 += bfhi(v6);
            ax3 += bflo(v7); ay3 += bfhi(v7);
        }
        for (; k < m; ++k) {
            int s0 = __shfl(myidx, k);
            unsigned int v0 = Hu[(size_t)s0 * 64 + lane];
            ax0 += bflo(v0); ay0 += bfhi(v0);
        }
    }
    int d0 = lane * 2;
    float sc = cnt > 0 ? 1.0f / sqrtf((float)cnt) : 0.0f;
    float2 cbv = *(const float2*)(cb + d0);
    float2 x;
    x.x = (ax0 + ax1 + ax2 + ax3) * sc + cbv.x;
    x.y = (ay0 + ay1 + ay2 + ay3) * sc + cbv.y;

    float s = x.x + x.y;
#pragma unroll
    for (int mm = 32; mm >= 1; mm >>= 1) s += __shfl_xor(s, mm, 64);
    float mu = s * (1.0f / 128.0f);
    float dx = x.x - mu, dy = x.y - mu;
    float v = dx * dx + dy * dy;
#pragma unroll
    for (int mm = 32; mm >= 1; mm >>= 1) v += __shfl_xor(v, mm, 64);
    float inv = 1.0f / sqrtf(v * (1.0f / 128.0f) + LN_EPS);
    float2 gv = *(const float2*)(g + d0);
    float2 bv = *(const float2*)(bt + d0);
    float y0 = dx * inv * gv.x + bv.x;
    float y1 = dy * inv * gv.y + bv.y;
    if (MODE == 1) {
        y0 = fmaxf(y0, 0.0f);
        y1 = fmaxf(y1, 0.0f);
    } else {
        *(float2*)(out_f32 + (size_t)gw * 128 + d0) = make_float2(y0, y1);
    }
    ((unsigned int*)out_bf)[(size_t)gw * 64 + lane] = pack2bf(y0, y1);
}

// ---------------- classifier: logits[n,C] = Z_bf16 @ W + b ----------------
__global__ __launch_bounds__(256) void k_cls(const unsigned short* __restrict__ Z, const float* __restrict__ W,
                                             const float* __restrict__ b, float* __restrict__ out,
                                             int n, int C) {
    int gpos = blockIdx.x * blockDim.x + threadIdx.x;
    int row = gpos >> 4, c = gpos & 15;
    if (row >= n || c >= C) return;
    const unsigned int* zr = (const unsigned int*)(Z + (size_t)row * 128);
    float acc = b[c];
#pragma unroll 8
    for (int kk = 0; kk < 64; ++kk) {
        unsigned int v = zr[kk];
        acc = fmaf(bflo(v), W[(2 * kk) * C + c], acc);
        acc = fmaf(bfhi(v), W[(2 * kk + 1) * C + c], acc);
    }
    out[(size_t)row * C + c] = acc;
}

extern "C" void kernel_launch(void* const* d_in, const int* in_sizes, int n_in,
                              void* d_out, int out_size, void* d_ws, size_t ws_size,
                              hipStream_t stream) {
    const float* feat  = (const float*)d_in[0];
    const float* noise = (const float*)d_in[1];
    const int*   nmask = (const int*)d_in[2];
    const int*   src   = (const int*)d_in[3];
    const int*   dst   = (const int*)d_in[4];
    const float* token = (const float*)d_in[5];
    const float* W0    = (const float*)d_in[6];
    const float* b0    = (const float*)d_in[7];
    const float* ln0g  = (const float*)d_in[8];
    const float* ln0b  = (const float*)d_in[9];
    const float* W1    = (const float*)d_in[10];
    const float* b1    = (const float*)d_in[11];
    const float* ln1g  = (const float*)d_in[12];
    const float* ln1b  = (const float*)d_in[13];
    const float* dW1   = (const float*)d_in[14];
    const float* db1   = (const float*)d_in[15];
    const float* dW2   = (const float*)d_in[16];
    const float* db2   = (const float*)d_in[17];
    const float* cW    = (const float*)d_in[18];
    const float* cbias = (const float*)d_in[19];

    const int N = in_sizes[0] / 128;
    const int E = in_sizes[3];
    const int C = in_sizes[19];
    const size_t ND = (size_t)N * 128;
    const int NBUCK = (N + BROWS - 1) / BROWS;  // 782 for N=50000 (<= 1024)

    float* out       = (float*)d_out;
    float* out_recon = out;
    float* out_feat  = out + ND;
    float* out_mask  = out + 2 * ND;
    float* out_z     = out + 2 * ND + N;
    float* out_log   = out + 3 * ND + N;

    char* w = (char*)d_ws;
    unsigned short* bufX = (unsigned short*)w; w += ND * 2;   // bf16 ping
    unsigned short* bufH = (unsigned short*)w; w += ND * 2;   // bf16 pong
    unsigned short* zbf  = (unsigned short*)w; w += ND * 2;   // bf16 z
    unsigned short* wpack = (unsigned short*)w; w += (size_t)4 * WPSTRIDE * 2;  // packed weights
    float* doutv   = (float*)w; w += (size_t)N * 4;
    int* row_ptr   = (int*)w;   w += (size_t)(N + 4) * 4;
    int* csr_src   = (int*)w;   w += (size_t)E * 4;
    int* scratch   = (int*)w;   // union: HB*N hist partials, then binning structures

    // phase-1 view
    int* partials = scratch;
    // phase-2 view (sequential on stream)
    uint2* binned = (uint2*)scratch;                          // E entries (8B-aligned)
    int* counts = scratch + (size_t)2 * E;                    // NBUCK*NBLK
    int* tot    = counts + (size_t)NBUCK * NBLK;              // NBUCK
    int* base   = tot + NBUCK;                                // NBUCK+1
    int* offs   = base + NBUCK + 2;                           // NBUCK*NBLK

    int nb = (N + 255) / 256;

    // weight pre-pack (W0, W1, dW1, dW2)
    k_pack<<<256, 256, 0, stream>>>(W0, W1, dW1, dW2, wpack);

    // out-degree (atomic-free) -> doutv
    k_hist<<<HB, 512, 0, stream>>>(src, partials, N, E);
    k_hist_reduce<<<nb, 256, 0, stream>>>(partials, doutv, N);

    // dst-bucket counting sort (LDS atomics only)
    k_binA<<<NBLK, 256, 0, stream>>>(dst, counts, NBUCK, E);
    k_binB1<<<NBUCK, 128, 0, stream>>>(counts, tot);
    k_binB2<<<1, 1024, 0, stream>>>(tot, base, NBUCK, E);
    k_binB3<<<NBUCK, 128, 0, stream>>>(counts, base, offs);
    k_binC<<<NBLK, 256, 0, stream>>>(src, dst, offs, binned, NBUCK, E);
    // per-bucket CSR finalize
    k_csr<<<NBUCK, 256, 0, stream>>>(binned, base, row_ptr, csr_src, N);

    k_prep<<<(N * 32 + 255) / 256, 256, 0, stream>>>(feat, noise, nmask, token,
                                                     bufX, out_feat, out_mask, N);

    int gb = (N + 127) / 128;
    int rb = (N * 64 + 255) / 256;

    // layer 0: H = (X@W0)*dout[row]; wave-per-row agg + LN + relu
    k_gemm_mfma<0, 1, 1><<<gb, 256, 0, stream>>>(bufX, wpack + 0 * WPSTRIDE, nullptr, doutv, bufH, N);
    k_agg_ln<1><<<rb, 256, 0, stream>>>(bufH, row_ptr, csr_src, b0, ln0g, ln0b, nullptr, bufX, N);

    // layer 1: H = (h@W1)*dout[row]; agg + LN -> z
    k_gemm_mfma<0, 1, 1><<<gb, 256, 0, stream>>>(bufX, wpack + 1 * WPSTRIDE, nullptr, doutv, bufH, N);
    k_agg_ln<0><<<rb, 256, 0, stream>>>(bufH, row_ptr, csr_src, b1, ln1g, ln1b, out_z, zbf, N);

    // decoder
    k_gemm_mfma<2, 1, 0><<<gb, 256, 0, stream>>>(zbf, wpack + 2 * WPSTRIDE, db1, nullptr, bufX, N);
    k_gemm_mfma<1, 0, 0><<<gb, 256, 0, stream>>>(bufX, wpack + 3 * WPSTRIDE, db2, nullptr, out_recon, N);

    // classifier
    k_cls<<<(N * 16 + 255) / 256, 256, 0, stream>>>(zbf, cW, cbias, out_log, N, C);
}

// Round 8
// 217.983 us; speedup vs baseline: 7.1803x; 1.1479x over previous
//
#include <hip/hip_runtime.h>
#include <hip/hip_bf16.h>

#define LN_EPS 1e-5f
#define HB 64          // histogram edge-chunks (power of 2)
#define HSEG 12800     // histogram LDS segment (51.2 KB)
#define NBLK 128       // binning blocks
#define BROWS 64       // rows per dst bucket
#define WPSTRIDE 17408 // 128*136 shorts per packed weight

typedef __attribute__((ext_vector_type(8))) short short8;
typedef __attribute__((ext_vector_type(4))) float f32x4;

// ---- bf16 helpers (bit-level, RNE) ----
__device__ __forceinline__ unsigned short f2bf(float f) {
    unsigned int u = __float_as_uint(f);
    u += 0x7fffu + ((u >> 16) & 1u);
    return (unsigned short)(u >> 16);
}
__device__ __forceinline__ unsigned int pack2bf(float a, float b) {
    return (unsigned int)f2bf(a) | ((unsigned int)f2bf(b) << 16);
}
__device__ __forceinline__ float bflo(unsigned int v) { return __uint_as_float(v << 16); }
__device__ __forceinline__ float bfhi(unsigned int v) { return __uint_as_float(v & 0xffff0000u); }

// ---------------- weight pre-pack: W[k][c] f32 -> Wp[c*136+k] bf16 (4 weights) ----------------
__global__ __launch_bounds__(256) void k_pack(const float* __restrict__ Wa, const float* __restrict__ Wb,
                                              const float* __restrict__ Wc, const float* __restrict__ Wd,
                                              unsigned short* __restrict__ dst) {
    int wsel = blockIdx.x >> 6;
    int idx = (blockIdx.x & 63) * 256 + threadIdx.x;   // 0..16383
    const float* W = wsel == 0 ? Wa : wsel == 1 ? Wb : wsel == 2 ? Wc : Wd;
    int c = idx >> 7, kk = idx & 127;
    dst[(size_t)wsel * WPSTRIDE + c * 136 + kk] = f2bf(W[kk * 128 + c]);
}

// ---------------- out-degree histogram, 2-D grid (chunk, segment); LDS atomics only ----------------
__global__ __launch_bounds__(512) void k_hist(const int* __restrict__ src, int* __restrict__ partials,
                                              int N, int E) {
    __shared__ int h[HSEG];
    int chunk = blockIdx.x & (HB - 1);
    int seg = blockIdx.x >> 6;           // log2(HB)=6
    int lo = seg * HSEG;
    int len = N - lo;
    if (len > HSEG) len = HSEG;
    if (len <= 0) return;
    for (int i = threadIdx.x; i < len; i += 512) h[i] = 0;
    __syncthreads();
    int per = (E + HB - 1) / HB;
    int e0 = chunk * per, e1 = min(e0 + per, E);
    for (int e = e0 + threadIdx.x; e < e1; e += 512) {
        int s = src[e] - lo;
        if ((unsigned)s < (unsigned)len) atomicAdd(&h[s], 1);  // LDS atomic
    }
    __syncthreads();
    for (int i = threadIdx.x; i < len; i += 512)
        partials[(size_t)chunk * N + lo + i] = h[i];
}

__global__ __launch_bounds__(256) void k_hist_reduce(const int* __restrict__ partials,
                                                     float* __restrict__ doutv, int N) {
    int i = blockIdx.x * 256 + threadIdx.x;
    if (i >= N) return;
    int s = 0;
#pragma unroll
    for (int b = 0; b < HB; ++b) s += partials[(size_t)b * N + i];
    doutv[i] = s > 0 ? 1.0f / sqrtf((float)s) : 0.0f;
}

// ---------------- edge binning by dst bucket (counting sort, LDS atomics only) ----------------
__global__ __launch_bounds__(256) void k_binA(const int* __restrict__ dst, int* __restrict__ counts,
                                              int nbuck, int E) {
    __shared__ int h[1024];
    for (int i = threadIdx.x; i < nbuck; i += 256) h[i] = 0;
    __syncthreads();
    int per = (E + NBLK - 1) / NBLK;
    int e0 = blockIdx.x * per, e1 = min(e0 + per, E);
    for (int e = e0 + threadIdx.x; e < e1; e += 256) atomicAdd(&h[dst[e] >> 6], 1);
    __syncthreads();
    for (int i = threadIdx.x; i < nbuck; i += 256) counts[(size_t)i * NBLK + blockIdx.x] = h[i];
}

__global__ __launch_bounds__(128) void k_binB1(const int* __restrict__ counts, int* __restrict__ tot) {
    __shared__ int sm[128];
    int t = threadIdx.x;
    sm[t] = counts[(size_t)blockIdx.x * NBLK + t];
    __syncthreads();
#pragma unroll
    for (int o = 64; o >= 1; o >>= 1) {
        if (t < o) sm[t] += sm[t + o];
        __syncthreads();
    }
    if (t == 0) tot[blockIdx.x] = sm[0];
}

__global__ __launch_bounds__(1024) void k_binB2(const int* __restrict__ tot, int* __restrict__ base,
                                                int nbuck, int E) {
    __shared__ int sm[1024];
    int t = threadIdx.x;
    int v = (t < nbuck) ? tot[t] : 0;
    sm[t] = v;
    __syncthreads();
    for (int o = 1; o < 1024; o <<= 1) {
        int u = (t >= o) ? sm[t - o] : 0;
        __syncthreads();
        sm[t] += u;
        __syncthreads();
    }
    if (t < nbuck) base[t] = sm[t] - v;  // exclusive
    if (t == 0) base[nbuck] = E;
}

__global__ __launch_bounds__(128) void k_binB3(const int* __restrict__ counts, const int* __restrict__ base,
                                               int* __restrict__ offs) {
    __shared__ int sm[128];
    int t = threadIdx.x;
    int v = counts[(size_t)blockIdx.x * NBLK + t];
    sm[t] = v;
    __syncthreads();
    for (int o = 1; o < 128; o <<= 1) {
        int u = (t >= o) ? sm[t - o] : 0;
        __syncthreads();
        sm[t] += u;
        __syncthreads();
    }
    offs[(size_t)blockIdx.x * NBLK + t] = base[blockIdx.x] + sm[t] - v;
}

__global__ __launch_bounds__(256) void k_binC(const int* __restrict__ src, const int* __restrict__ dst,
                                              const int* __restrict__ offs, uint2* __restrict__ binned,
                                              int nbuck, int E) {
    __shared__ int cur[1024];
    for (int i = threadIdx.x; i < nbuck; i += 256) cur[i] = offs[(size_t)i * NBLK + blockIdx.x];
    __syncthreads();
    int per = (E + NBLK - 1) / NBLK;
    int e0 = blockIdx.x * per, e1 = min(e0 + per, E);
    for (int e = e0 + threadIdx.x; e < e1; e += 256) {
        int d = dst[e];
        int p = atomicAdd(&cur[d >> 6], 1);  // LDS atomic
        binned[p] = make_uint2((unsigned)src[e], (unsigned)d);
    }
}

// ---------------- per-bucket CSR build (LDS atomics only): row_ptr + csr_src ----------------
__global__ __launch_bounds__(256) void k_csr(const uint2* __restrict__ binned, const int* __restrict__ base,
                                             int* __restrict__ row_ptr, int* __restrict__ csr_src, int N) {
    __shared__ int hcnt[BROWS], ccur[BROWS];
    int b = blockIdx.x, t = threadIdx.x;
    int e0 = base[b], e1 = base[b + 1];
    if (t < BROWS) hcnt[t] = 0;
    __syncthreads();
    for (int e = e0 + t; e < e1; e += 256)
        atomicAdd(&hcnt[binned[e].y & (BROWS - 1)], 1);
    __syncthreads();
    if (t < BROWS) {
        int acc = 0;
        for (int r = 0; r < t; ++r) acc += hcnt[r];
        ccur[t] = acc;
        int gw = b * BROWS + t;
        if (gw <= N) row_ptr[gw] = e0 + acc;   // last bucket's overhang writes row_ptr[N]
    }
    __syncthreads();
    for (int e = e0 + t; e < e1; e += 256) {
        uint2 ed = binned[e];
        int p = atomicAdd(&ccur[ed.y & (BROWS - 1)], 1);
        csr_src[e0 + p] = (int)ed.x;
    }
}

// ---------------- prep: mask+noise -> xs (bf16); feat copy; mask float ----------------
__global__ __launch_bounds__(256) void k_prep(const float* __restrict__ feat, const float* __restrict__ noise,
                                              const int* __restrict__ mask, const float* __restrict__ token,
                                              unsigned short* __restrict__ xs, float* __restrict__ feat_out,
                                              float* __restrict__ mask_out, int n) {
    int i = blockIdx.x * blockDim.x + threadIdx.x;
    int total = n * 32;
    if (i >= total) return;
    int row = i >> 5, q = i & 31;
    float4 f = ((const float4*)feat)[i];
    float4 nz = ((const float4*)noise)[i];
    bool m = mask[row] != 0;
    float4 b = f;
    if (m) b = ((const float4*)token)[q];
    uint2 p;
    p.x = pack2bf(b.x + 0.1f * nz.x, b.y + 0.1f * nz.y);
    p.y = pack2bf(b.z + 0.1f * nz.z, b.w + 0.1f * nz.w);
    ((uint2*)xs)[i] = p;
    ((float4*)feat_out)[i] = f;
    if (q == 0) mask_out[row] = m ? 1.0f : 0.0f;
}

// ---------------- MFMA GEMM with pre-packed bf16 weights ----------------
// C[n,128] = A_bf16[n,128] @ Wp (*dout[row])(+bias)(+relu)
template <int EPI, int OUT_BF16, int DOUT>
__global__ __launch_bounds__(256) void k_gemm_mfma(const unsigned short* __restrict__ A,
                                                   const unsigned short* __restrict__ Wp,
                                                   const float* __restrict__ bias,
                                                   const float* __restrict__ dscale,
                                                   void* __restrict__ Cout, int n) {
    __shared__ uint4 BtV[2176];  // 128*136 bf16 = 34816 B
    unsigned short* Bt = (unsigned short*)BtV;
    int tid = threadIdx.x;
    const uint4* Wv = (const uint4*)Wp;
    for (int i = tid; i < 2176; i += 256) BtV[i] = Wv[i];
    __syncthreads();

    int wid = tid >> 6, lane = tid & 63;
    int q = lane >> 4, m = lane & 15;
    int r0 = blockIdx.x * 128 + wid * 32;

    f32x4 acc[2][8];
#pragma unroll
    for (int i = 0; i < 2; ++i)
#pragma unroll
        for (int j = 0; j < 8; ++j) acc[i][j] = (f32x4){0.f, 0.f, 0.f, 0.f};

#pragma unroll
    for (int ks = 0; ks < 4; ++ks) {
        int k0 = ks * 32 + q * 8;
        short8 a[2];
#pragma unroll
        for (int i = 0; i < 2; ++i) {
            int row = r0 + i * 16 + m;
            if (row > n - 1) row = n - 1;  // clamp; discarded at store
            a[i] = *(const short8*)(A + (size_t)row * 128 + k0);
        }
        short8 b[8];
#pragma unroll
        for (int j = 0; j < 8; ++j)
            b[j] = *(const short8*)(&Bt[(j * 16 + m) * 136 + k0]);
#pragma unroll
        for (int i = 0; i < 2; ++i)
#pragma unroll
            for (int j = 0; j < 8; ++j)
                acc[i][j] = __builtin_amdgcn_mfma_f32_16x16x32_bf16(a[i], b[j], acc[i][j], 0, 0, 0);
    }

    float bv[8];
    if (EPI >= 1) {
#pragma unroll
        for (int j = 0; j < 8; ++j) bv[j] = bias[j * 16 + m];
    }

#pragma unroll
    for (int i = 0; i < 2; ++i) {
#pragma unroll
        for (int r = 0; r < 4; ++r) {
            int row = r0 + i * 16 + q * 4 + r;
            if (row < n) {
                float ds = DOUT ? dscale[row] : 1.0f;
#pragma unroll
                for (int j = 0; j < 8; ++j) {
                    float v = acc[i][j][r];
                    if (DOUT) v *= ds;
                    if (EPI >= 1) v += bv[j];
                    if (EPI == 2) v = fmaxf(v, 0.0f);
                    if (OUT_BF16)
                        ((unsigned short*)Cout)[(size_t)row * 128 + j * 16 + m] = f2bf(v);
                    else
                        ((float*)Cout)[(size_t)row * 128 + j * 16 + m] = v;
                }
            }
        }
    }
}

// ---------------- fused CSR agg (lane-parallel indices, 8-deep gather) + LN (+relu) ----------------
// MODE 1: out_bf = bf16( relu(LN(agg*din+cb)) )
// MODE 0: out_f32 = LN(agg*din+cb)  AND  out_bf = bf16(z)
template <int MODE>
__global__ __launch_bounds__(256) void k_agg_ln(const unsigned short* __restrict__ H,
                                                const int* __restrict__ row_ptr,
                                                const int* __restrict__ csr_src,
                                                const float* __restrict__ cb, const float* __restrict__ g,
                                                const float* __restrict__ bt,
                                                float* __restrict__ out_f32, unsigned short* __restrict__ out_bf,
                                                int n) {
    int gw = (blockIdx.x * blockDim.x + threadIdx.x) >> 6;
    int lane = threadIdx.x & 63;
    if (gw >= n) return;
    int beg = row_ptr[gw], end = row_ptr[gw + 1];
    int cnt = end - beg;
    const unsigned int* Hu = (const unsigned int*)H;
    float ax0 = 0.f, ay0 = 0.f, ax1 = 0.f, ay1 = 0.f;
    float ax2 = 0.f, ay2 = 0.f, ax3 = 0.f, ay3 = 0.f;
    for (int c0 = beg; c0 < end; c0 += 64) {
        int m = end - c0;
        if (m > 64) m = 64;
        int myidx = (lane < m) ? csr_src[c0 + lane] : 0;  // one coalesced index load per 64 edges
        int k = 0;
        for (; k + 7 < m; k += 8) {
            int s0 = __shfl(myidx, k + 0), s1 = __shfl(myidx, k + 1);
            int s2 = __shfl(myidx, k + 2), s3 = __shfl(myidx, k + 3);
            int s4 = __shfl(myidx, k + 4), s5 = __shfl(myidx, k + 5);
            int s6 = __shfl(myidx, k + 6), s7 = __shfl(myidx, k + 7);
            unsigned int v0 = Hu[(size_t)s0 * 64 + lane];
            unsigned int v1 = Hu[(size_t)s1 * 64 + lane];
            unsigned int v2 = Hu[(size_t)s2 * 64 + lane];
            unsigned int v3 = Hu[(size_t)s3 * 64 + lane];
            unsigned int v4 = Hu[(size_t)s4 * 64 + lane];
            unsigned int v5 = Hu[(size_t)s5 * 64 + lane];
            unsigned int v6 = Hu[(size_t)s6 * 64 + lane];
            unsigned int v7 = Hu[(size_t)s7 * 64 + lane];
            ax0 += bflo(v0); ay0 += bfhi(v0);
            ax1 += bflo(v1); ay1 += bfhi(v1);
            ax2 += bflo(v2); ay2 += bfhi(v2);
            ax3 += bflo(v3); ay3 += bfhi(v3);
            ax0 += bflo(v4); ay0 += bfhi(v4);
            ax1 += bflo(v5); ay1 += bfhi(v5);
            ax2 += bflo(v6); ay2 += bfhi(v6);
            ax3 += bflo(v7); ay3 += bfhi(v7);
        }
        for (; k < m; ++k) {
            int s0 = __shfl(myidx, k);
            unsigned int v0 = Hu[(size_t)s0 * 64 + lane];
            ax0 += bflo(v0); ay0 += bfhi(v0);
        }
    }
    int d0 = lane * 2;
    float sc = cnt > 0 ? 1.0f / sqrtf((float)cnt) : 0.0f;
    float2 cbv = *(const float2*)(cb + d0);
    float2 x;
    x.x = (ax0 + ax1 + ax2 + ax3) * sc + cbv.x;
    x.y = (ay0 + ay1 + ay2 + ay3) * sc + cbv.y;

    float s = x.x + x.y;
#pragma unroll
    for (int mm = 32; mm >= 1; mm >>= 1) s += __shfl_xor(s, mm, 64);
    float mu = s * (1.0f / 128.0f);
    float dx = x.x - mu, dy = x.y - mu;
    float v = dx * dx + dy * dy;
#pragma unroll
    for (int mm = 32; mm >= 1; mm >>= 1) v += __shfl_xor(v, mm, 64);
    float inv = 1.0f / sqrtf(v * (1.0f / 128.0f) + LN_EPS);
    float2 gv = *(const float2*)(g + d0);
    float2 bv = *(const float2*)(bt + d0);
    float y0 = dx * inv * gv.x + bv.x;
    float y1 = dy * inv * gv.y + bv.y;
    if (MODE == 1) {
        y0 = fmaxf(y0, 0.0f);
        y1 = fmaxf(y1, 0.0f);
    } else {
        *(float2*)(out_f32 + (size_t)gw * 128 + d0) = make_float2(y0, y1);
    }
    ((unsigned int*)out_bf)[(size_t)gw * 64 + lane] = pack2bf(y0, y1);
}

// ---------------- classifier: logits[n,C] = Z_bf16 @ W + b ----------------
__global__ __launch_bounds__(256) void k_cls(const unsigned short* __restrict__ Z, const float* __restrict__ W,
                                             const float* __restrict__ b, float* __restrict__ out,
                                             int n, int C) {
    int gpos = blockIdx.x * blockDim.x + threadIdx.x;
    int row = gpos >> 4, c = gpos & 15;
    if (row >= n || c >= C) return;
    const unsigned int* zr = (const unsigned int*)(Z + (size_t)row * 128);
    float acc = b[c];
#pragma unroll 8
    for (int kk = 0; kk < 64; ++kk) {
        unsigned int v = zr[kk];
        acc = fmaf(bflo(v), W[(2 * kk) * C + c], acc);
        acc = fmaf(bfhi(v), W[(2 * kk + 1) * C + c], acc);
    }
    out[(size_t)row * C + c] = acc;
}

extern "C" void kernel_launch(void* const* d_in, const int* in_sizes, int n_in,
                              void* d_out, int out_size, void* d_ws, size_t ws_size,
                              hipStream_t stream) {
    const float* feat  = (const float*)d_in[0];
    const float* noise = (const float*)d_in[1];
    const int*   nmask = (const int*)d_in[2];
    const int*   src   = (const int*)d_in[3];
    const int*   dst   = (const int*)d_in[4];
    const float* token = (const float*)d_in[5];
    const float* W0    = (const float*)d_in[6];
    const float* b0    = (const float*)d_in[7];
    const float* ln0g  = (const float*)d_in[8];
    const float* ln0b  = (const float*)d_in[9];
    const float* W1    = (const float*)d_in[10];
    const float* b1    = (const float*)d_in[11];
    const float* ln1g  = (const float*)d_in[12];
    const float* ln1b  = (const float*)d_in[13];
    const float* dW1   = (const float*)d_in[14];
    const float* db1   = (const float*)d_in[15];
    const float* dW2   = (const float*)d_in[16];
    const float* db2   = (const float*)d_in[17];
    const float* cW    = (const float*)d_in[18];
    const float* cbias = (const float*)d_in[19];

    const int N = in_sizes[0] / 128;
    const int E = in_sizes[3];
    const int C = in_sizes[19];
    const size_t ND = (size_t)N * 128;
    const int NBUCK = (N + BROWS - 1) / BROWS;  // 782 for N=50000 (<= 1024)
    const int NSEG = (N + HSEG - 1) / HSEG;     // 4 for N=50000

    float* out       = (float*)d_out;
    float* out_recon = out;
    float* out_feat  = out + ND;
    float* out_mask  = out + 2 * ND;
    float* out_z     = out + 2 * ND + N;
    float* out_log   = out + 3 * ND + N;

    char* w = (char*)d_ws;
    unsigned short* bufX = (unsigned short*)w; w += ND * 2;   // bf16 ping
    unsigned short* bufH = (unsigned short*)w; w += ND * 2;   // bf16 pong
    unsigned short* zbf  = (unsigned short*)w; w += ND * 2;   // bf16 z
    unsigned short* wpack = (unsigned short*)w; w += (size_t)4 * WPSTRIDE * 2;  // packed weights
    float* doutv   = (float*)w; w += (size_t)N * 4;
    int* row_ptr   = (int*)w;   w += (size_t)(N + 4) * 4;
    int* csr_src   = (int*)w;   w += (size_t)E * 4;
    int* scratch   = (int*)w;   // union: HB*N hist partials, then binning structures

    // phase-1 view
    int* partials = scratch;
    // phase-2 view (sequential on stream)
    uint2* binned = (uint2*)scratch;                          // E entries (8B-aligned)
    int* counts = scratch + (size_t)2 * E;                    // NBUCK*NBLK
    int* tot    = counts + (size_t)NBUCK * NBLK;              // NBUCK
    int* base   = tot + NBUCK;                                // NBUCK+1
    int* offs   = base + NBUCK + 2;                           // NBUCK*NBLK

    int nb = (N + 255) / 256;

    // weight pre-pack (W0, W1, dW1, dW2)
    k_pack<<<256, 256, 0, stream>>>(W0, W1, dW1, dW2, wpack);

    // out-degree (LDS atomics, 2-D grid) -> doutv
    k_hist<<<HB * NSEG, 512, 0, stream>>>(src, partials, N, E);
    k_hist_reduce<<<nb, 256, 0, stream>>>(partials, doutv, N);

    // dst-bucket counting sort (LDS atomics only)
    k_binA<<<NBLK, 256, 0, stream>>>(dst, counts, NBUCK, E);
    k_binB1<<<NBUCK, 128, 0, stream>>>(counts, tot);
    k_binB2<<<1, 1024, 0, stream>>>(tot, base, NBUCK, E);
    k_binB3<<<NBUCK, 128, 0, stream>>>(counts, base, offs);
    k_binC<<<NBLK, 256, 0, stream>>>(src, dst, offs, binned, NBUCK, E);
    // per-bucket CSR finalize
    k_csr<<<NBUCK, 256, 0, stream>>>(binned, base, row_ptr, csr_src, N);

    k_prep<<<(N * 32 + 255) / 256, 256, 0, stream>>>(feat, noise, nmask, token,
                                                     bufX, out_feat, out_mask, N);

    int gb = (N + 127) / 128;
    int rb = (N * 64 + 255) / 256;

    // layer 0: H = (X@W0)*dout[row]; wave-per-row agg + LN + relu
    k_gemm_mfma<0, 1, 1><<<gb, 256, 0, stream>>>(bufX, wpack + 0 * WPSTRIDE, nullptr, doutv, bufH, N);
    k_agg_ln<1><<<rb, 256, 0, stream>>>(bufH, row_ptr, csr_src, b0, ln0g, ln0b, nullptr, bufX, N);

    // layer 1: H = (h@W1)*dout[row]; agg + LN -> z
    k_gemm_mfma<0, 1, 1><<<gb, 256, 0, stream>>>(bufX, wpack + 1 * WPSTRIDE, nullptr, doutv, bufH, N);
    k_agg_ln<0><<<rb, 256, 0, stream>>>(bufH, row_ptr, csr_src, b1, ln1g, ln1b, out_z, zbf, N);

    // decoder
    k_gemm_mfma<2, 1, 0><<<gb, 256, 0, stream>>>(zbf, wpack + 2 * WPSTRIDE, db1, nullptr, bufX, N);
    k_gemm_mfma<1, 0, 0><<<gb, 256, 0, stream>>>(bufX, wpack + 3 * WPSTRIDE, db2, nullptr, out_recon, N);

    // classifier
    k_cls<<<(N * 16 + 255) / 256, 256, 0, stream>>>(zbf, cW, cbias, out_log, N, C);
}